// Round 1
// 1652.549 us; speedup vs baseline: 1.3157x; 1.3157x over previous
//
#include <hip/hip_runtime.h>
#include <hip/hip_bf16.h>
#include <math.h>

typedef __hip_bfloat16 bf16;
typedef _Float16 f16;
typedef __attribute__((ext_vector_type(8))) _Float16 f16x8;
typedef __attribute__((ext_vector_type(4))) float f32x4;

#define B_ 32
#define HW_ 784
#define T_ 785
#define TP_ 197
#define C_ 384
#define H_ 8
#define D_ 48
#define FF_ 1536
#define CH_ 64    // (b,h) pairs per attention chunk
#define SP_ 788   // padded S row stride (floats)
#define PVT_ 800  // padded P row stride (halfs), zero-filled 785..799

#define MFMA16(a, b, c) __builtin_amdgcn_mfma_f32_16x16x32_f16(a, b, c, 0, 0, 0)

// ---------------- sizes (elements) ----------------
static constexpr size_t NRES = (size_t)B_ * T_ * C_;
static constexpr size_t NX   = (size_t)B_ * HW_ * C_;
static constexpr size_t NCLS = (size_t)B_ * C_;
static constexpr size_t NLN1 = (size_t)T_ * C_;
static constexpr size_t NWP  = (size_t)C_ * C_;
static constexpr size_t NLN2 = (size_t)TP_ * C_;
static constexpr size_t NW1  = (size_t)FF_ * C_;
static constexpr size_t NX2  = (size_t)B_ * TP_ * C_;
static constexpr size_t NH   = (size_t)B_ * TP_ * FF_;

// ---------------- arena byte offsets ----------------
static constexpr size_t XF_OFF   = 0;
static constexpr size_t CLSF_OFF = XF_OFF   + NX   * 4;
static constexpr size_t LN1W_OFF = CLSF_OFF + NCLS * 4;
static constexpr size_t LN1B_OFF = LN1W_OFF + NLN1 * 4;
static constexpr size_t WQF_OFF  = LN1B_OFF + NLN1 * 4;   // Wq,Wk,Wv,Wo contiguous fp32
static constexpr size_t WKF_OFF  = WQF_OFF  + NWP  * 4;
static constexpr size_t WVF_OFF  = WKF_OFF  + NWP  * 4;
static constexpr size_t WOF_OFF  = WVF_OFF  + NWP  * 4;
static constexpr size_t LN2W_OFF = WOF_OFF  + NWP  * 4;
static constexpr size_t LN2B_OFF = LN2W_OFF + NLN2 * 4;
static constexpr size_t W1F_OFF  = LN2B_OFF + NLN2 * 4;
static constexpr size_t W2F_OFF  = W1F_OFF  + NW1  * 4;
static constexpr size_t X1_OFF   = W2F_OFF  + NW1  * 4;   // fp16 hi plane [NRES] + lo plane [NRES]
static constexpr size_t Q_OFF    = X1_OFF   + NRES * 4;   // per-head planes [b,h,t,48] hi+lo
static constexpr size_t K_OFF    = Q_OFF    + NRES * 4;
static constexpr size_t V_OFF    = K_OFF    + NRES * 4;
static constexpr size_t ATT_OFF  = V_OFF    + NRES * 4;   // row-major [M1][C] hi+lo
static constexpr size_t XM_OFF   = ATT_OFF  + NRES * 4;   // fp32
static constexpr size_t RES_OFF  = XM_OFF   + NRES * 4;   // fp32
static constexpr size_t X2N_OFF  = RES_OFF  + NRES * 4;   // fp32 (residual for FFN2)
static constexpr size_t H_OFF    = X2N_OFF  + NX2  * 4;   // fp16 hi [NH] + lo [NH]
static constexpr size_t MU_OFF   = H_OFF    + NH   * 4;
static constexpr size_t RS_OFF   = MU_OFF   + 128;
static constexpr size_t CID_OFF  = RS_OFF   + 128;
static constexpr size_t CAD_OFF  = CID_OFF  + NCLS * 8;
static constexpr size_t PERM_OFF = CAD_OFF  + (size_t)B_ * HW_ * 8;
static constexpr size_t FLAG_OFF = PERM_OFF + (size_t)B_ * (TP_ - 1) * 4;
static constexpr size_t PS_OFF   = FLAG_OFF + 16;
static constexpr size_t CIP_OFF  = PS_OFF + 32 * 16 * 16;
static constexpr size_t L2PS_OFF = CIP_OFF + (size_t)B_ * 8 * C_ * 8;
static constexpr size_t L2MU_OFF = L2PS_OFF + 32 * 8 * 16;
static constexpr size_t L2RS_OFF = L2MU_OFF + 128;
// fp16 split planes for weights / x2n
static constexpr size_t WPH_OFF  = L2RS_OFF + 128;                 // [4*NWP] hi (Wq,Wk,Wv,Wo)
static constexpr size_t WPL_OFF  = WPH_OFF  + 4 * NWP * 2;
static constexpr size_t WFH_OFF  = WPL_OFF  + 4 * NWP * 2;         // [2*NW1] hi (W1,W2)
static constexpr size_t WFL_OFF  = WFH_OFF  + 2 * NW1 * 2;
static constexpr size_t X2NH_OFF = WFL_OFF  + 2 * NW1 * 2;         // [NX2] hi
static constexpr size_t X2NL_OFF = X2NH_OFF + NX2 * 2;
static constexpr size_t S_OFF    = X2NL_OFF + NX2 * 2;             // fp32 S, CH*T*SP
static constexpr size_t PART_OFF = S_OFF;   // FFN2 split-K partials ALIAS dead S region
static constexpr size_t PH_OFF   = S_OFF  + (size_t)CH_ * T_ * SP_ * 4;  // P hi planes
static constexpr size_t PL_OFF   = PH_OFF + (size_t)CH_ * T_ * PVT_ * 2; // P lo planes
static constexpr size_t ARENA_BYTES = PL_OFF + (size_t)CH_ * T_ * PVT_ * 2;

__device__ __align__(256) unsigned char g_arena[ARENA_BYTES];

template <typename Tp>
__device__ __forceinline__ Tp* ap(size_t off) { return (Tp*)(g_arena + off); }

// fp16 split with denormal protection: v = hi + lo/4096.
// hi forced to 0 when |v| < 2^-14 so hi is never an fp16 denormal; lo is
// pre-scaled by 2^12 so it is normal for |residual| >= 2^-26. This keeps the
// scheme exact to ~2^-22 regardless of MFMA denormal-flush behavior.
__device__ __forceinline__ void splitf(float v, f16& h, f16& l)
{
    float a = fabsf(v);
    f16 hv = (a >= 6.103515625e-05f) ? (f16)v : (f16)0.f;
    h = hv;
    l = (f16)((v - (float)hv) * 4096.f);
}

// ---------------- dtype detect
__global__ void detect_kernel(const unsigned* __restrict__ w)
{
    if (threadIdx.x == 0)
        *ap<int>(FLAG_OFF) = (w[0] == 0x3F803F80u) ? 1 : 0;
}

// ---------------- single merged convert
struct SrcPtrs { const void* p[12]; };
static constexpr size_t SEGB[13] = {
    0,
    NX,
    NX + NCLS,
    NX + NCLS + NLN1,
    NX + NCLS + 2 * NLN1,
    NX + NCLS + 2 * NLN1 + NWP,
    NX + NCLS + 2 * NLN1 + 2 * NWP,
    NX + NCLS + 2 * NLN1 + 3 * NWP,
    NX + NCLS + 2 * NLN1 + 4 * NWP,
    NX + NCLS + 2 * NLN1 + 4 * NWP + NLN2,
    NX + NCLS + 2 * NLN1 + 4 * NWP + 2 * NLN2,
    NX + NCLS + 2 * NLN1 + 4 * NWP + 2 * NLN2 + NW1,
    NX + NCLS + 2 * NLN1 + 4 * NWP + 2 * NLN2 + 2 * NW1,
};
static constexpr size_t NTOT_CVT = SEGB[12];

__global__ __launch_bounds__(256) void cvt_all_kernel(SrcPtrs sp)
{
    size_t i = (size_t)blockIdx.x * 256 + threadIdx.x;
    if (i >= NTOT_CVT) return;
    int seg = 0;
#pragma unroll
    for (int k = 1; k < 12; k++) seg += (i >= SEGB[k]);
    size_t li = i - SEGB[seg];
    const void* src = sp.p[seg];
    float v = (*ap<int>(FLAG_OFF))
        ? __bfloat162float(((const bf16*)src)[li])
        : ((const float*)src)[li];
    ap<float>(XF_OFF)[i] = v;
}

// ---------------- weight split (fp32 arena -> fp16 hi/lo planes)
__global__ __launch_bounds__(256) void cvt_wsplit_kernel()
{
    size_t i = (size_t)blockIdx.x * 256 + threadIdx.x;
    const size_t n1 = 4 * NWP;
    const size_t n2 = 2 * NW1;
    if (i >= n1 + n2) return;
    if (i < n1) {
        float v = ap<float>(WQF_OFF)[i];
        f16 h, l; splitf(v, h, l);
        ap<f16>(WPH_OFF)[i] = h;
        ap<f16>(WPL_OFF)[i] = l;
    } else {
        size_t j = i - n1;
        float v = ap<float>(W1F_OFF)[j];
        f16 h, l; splitf(v, h, l);
        ap<f16>(WFH_OFF)[j] = h;
        ap<f16>(WFL_OFF)[j] = l;
    }
}

__device__ __forceinline__ float xin_val(int b, int t, int c)
{
    return (t == 0) ? ap<float>(CLSF_OFF)[b * C_ + c]
                    : ap<float>(XF_OFF)[((size_t)b * HW_ + (t - 1)) * C_ + c];
}

// ---------------- LN1 stats A/B, apply
__global__ __launch_bounds__(256) void stats1a_kernel()
{
    const int TC = T_ * C_;
    const int SL = (TC + 15) / 16;
    int b = blockIdx.x, s = blockIdx.y, tid = threadIdx.x;
    int e0 = s * SL, e1 = min(e0 + SL, TC);
    __shared__ double r1[256], r2[256];
    double sm = 0.0, s2 = 0.0;
    for (int e = e0 + tid; e < e1; e += 256) {
        int t = e / C_, c = e - t * C_;
        double v = (double)xin_val(b, t, c);
        sm += v; s2 += v * v;
    }
    r1[tid] = sm; r2[tid] = s2; __syncthreads();
    for (int o = 128; o; o >>= 1) {
        if (tid < o) { r1[tid] += r1[tid + o]; r2[tid] += r2[tid + o]; }
        __syncthreads();
    }
    if (tid == 0) {
        double2* ps = ap<double2>(PS_OFF);
        ps[b * 16 + s] = make_double2(r1[0], r2[0]);
    }
}

__global__ __launch_bounds__(64) void stats1b_kernel()
{
    int b = blockIdx.x, lane = threadIdx.x;
    const double2* ps = ap<double2>(PS_OFF);
    double sm = 0.0, s2 = 0.0;
    if (lane < 16) { sm = ps[b * 16 + lane].x; s2 = ps[b * 16 + lane].y; }
    for (int o = 8; o; o >>= 1) { sm += __shfl_down(sm, o); s2 += __shfl_down(s2, o); }
    if (lane == 0) {
        const int TC = T_ * C_;
        double m = sm / TC;
        double var = s2 / TC - m * m;
        ap<float>(MU_OFF)[b] = (float)m;
        ap<float>(RS_OFF)[b] = (float)(1.0 / sqrt(var + 1e-5));
    }
}

__global__ __launch_bounds__(256) void ln1_apply_kernel()
{
    size_t i = (size_t)blockIdx.x * 256 + threadIdx.x;
    if (i >= NRES) return;
    int b = (int)(i / (T_ * C_));
    int rem = (int)(i - (size_t)b * T_ * C_);
    int t = rem / C_, c = rem - t * C_;
    float v = xin_val(b, t, c);
    float r = (v - ap<float>(MU_OFF)[b]) * ap<float>(RS_OFF)[b]
              * ap<float>(LN1W_OFF)[t * C_ + c]
              + ap<float>(LN1B_OFF)[t * C_ + c];
    f16 h, l; splitf(r, h, l);
    ap<f16>(X1_OFF)[i] = h;
    ap<f16>(X1_OFF)[NRES + i] = l;
}

// ---------------- split-fp16 MFMA GEMM, 128x128 tile, C = A * B^T
// A planes [M][K] hi/lo, B planes [N][K] hi/lo, all K-contiguous fp16.
// acc1 = hi*hi ; acc2 = hi*lo' + lo'*hi ; C = acc1 + acc2/4096.
// EMODE 2: gelu -> H planes; 4: XM fp32 + RES = v + x_in; 5: QKV head-plane
// routing; 6: split-K(2) fp32 partials.
template<int EMODE>
__global__ __launch_bounds__(256, 2) void gemm_mfma(
    size_t ah_off, size_t al_off, size_t bh_off, size_t bl_off,
    size_t c_off, int M, int N, int K)
{
    __shared__ f16 Ah[128][40], Al[128][40], Bh[128][40], Bl[128][40];
    const f16* gAh = ap<f16>(ah_off);
    const f16* gAl = ap<f16>(al_off);
    const f16* gBh = ap<f16>(bh_off);
    const f16* gBl = ap<f16>(bl_off);
    int bm = blockIdx.x * 128, bn = blockIdx.y * 128;
    int kbeg = 0, kend = K;
    if (EMODE == 6) { int ks = K >> 1; kbeg = blockIdx.z * ks; kend = kbeg + ks; }
    int tid = threadIdx.x;
    int srow = tid >> 1, sseg = tid & 1;
    int gmA = bm + srow;
    bool av = (gmA < M);
    const size_t aoff = (size_t)gmA * K + sseg * 16;
    const size_t boff = (size_t)(bn + srow) * K + sseg * 16;
    int w = tid >> 6, l = tid & 63;
    int wm = (w >> 1) * 64, wn = (w & 1) * 64;
    int lr = l & 15, lk = (l >> 4) * 8;

    const f32x4 zf = {0.f, 0.f, 0.f, 0.f};
    f32x4 acc1[4][4], acc2[4][4];
#pragma unroll
    for (int i = 0; i < 4; i++)
#pragma unroll
        for (int j = 0; j < 4; j++) { acc1[i][j] = zf; acc2[i][j] = zf; }
    const int4 zz = make_int4(0, 0, 0, 0);

    for (int k0 = kbeg; k0 < kend; k0 += 32) {
        size_t ka = aoff + k0, kb = boff + k0;
        int4 A0 = av ? *(const int4*)(gAh + ka)     : zz;
        int4 A1 = av ? *(const int4*)(gAh + ka + 8) : zz;
        int4 A2 = av ? *(const int4*)(gAl + ka)     : zz;
        int4 A3 = av ? *(const int4*)(gAl + ka + 8) : zz;
        int4 B0 = *(const int4*)(gBh + kb);
        int4 B1 = *(const int4*)(gBh + kb + 8);
        int4 B2 = *(const int4*)(gBl + kb);
        int4 B3 = *(const int4*)(gBl + kb + 8);
        *(int4*)&Ah[srow][sseg * 16]     = A0;
        *(int4*)&Ah[srow][sseg * 16 + 8] = A1;
        *(int4*)&Al[srow][sseg * 16]     = A2;
        *(int4*)&Al[srow][sseg * 16 + 8] = A3;
        *(int4*)&Bh[srow][sseg * 16]     = B0;
        *(int4*)&Bh[srow][sseg * 16 + 8] = B1;
        *(int4*)&Bl[srow][sseg * 16]     = B2;
        *(int4*)&Bl[srow][sseg * 16 + 8] = B3;
        __syncthreads();
        f16x8 fah[4], fal[4], fbh[4], fbl[4];
#pragma unroll
        for (int i = 0; i < 4; i++) {
            fah[i] = *(const f16x8*)&Ah[wm + i * 16 + lr][lk];
            fal[i] = *(const f16x8*)&Al[wm + i * 16 + lr][lk];
            fbh[i] = *(const f16x8*)&Bh[wn + i * 16 + lr][lk];
            fbl[i] = *(const f16x8*)&Bl[wn + i * 16 + lr][lk];
        }
#pragma unroll
        for (int i = 0; i < 4; i++)
#pragma unroll
            for (int j = 0; j < 4; j++) {
                acc1[i][j] = MFMA16(fah[i], fbh[j], acc1[i][j]);
                acc2[i][j] = MFMA16(fah[i], fbl[j], acc2[i][j]);
                acc2[i][j] = MFMA16(fal[i], fbh[j], acc2[i][j]);
            }
        __syncthreads();
    }

#pragma unroll
    for (int i = 0; i < 4; i++)
#pragma unroll
        for (int j = 0; j < 4; j++)
#pragma unroll
            for (int r = 0; r < 4; r++) {
                int row = bm + wm + i * 16 + ((l >> 4) << 2) + r;
                int col = bn + wn + j * 16 + lr;
                if (row >= M) continue;
                float v = acc1[i][j][r] + acc2[i][j][r] * 0.000244140625f;
                if (EMODE == 5) {
                    int seg = col / C_;
                    int cn = col - seg * C_;
                    int hh = cn / D_, dd = cn - hh * D_;
                    int b2 = row / T_, t2 = row - b2 * T_;
                    size_t idx = ((size_t)(b2 * H_ + hh) * T_ + t2) * D_ + dd;
                    f16* dst = (seg == 0) ? ap<f16>(Q_OFF)
                             : (seg == 1) ? ap<f16>(K_OFF) : ap<f16>(V_OFF);
                    f16 h, lo; splitf(v, h, lo);
                    dst[idx] = h;
                    dst[NRES + idx] = lo;
                } else if (EMODE == 4) {
                    ap<float>(c_off)[(size_t)row * N + col] = v;
                    int b2 = row / T_, t2 = row - b2 * T_;
                    ap<float>(RES_OFF)[(size_t)row * N + col] = v + xin_val(b2, t2, col);
                } else if (EMODE == 2) {
                    float g = 0.5f * v * (1.f + erff(v * 0.70710678f));
                    size_t idx = (size_t)row * N + col;
                    f16 h, lo; splitf(g, h, lo);
                    ap<f16>(H_OFF)[idx] = h;
                    ap<f16>(H_OFF)[NH + idx] = lo;
                } else {  // 6
                    ap<float>(PART_OFF)[(size_t)blockIdx.z * NX2 + (size_t)row * N + col] = v;
                }
            }
}

// ---------------- attention step 1: S = scale * Q K^T   (split MFMA, K=48)
__global__ __launch_bounds__(256, 2) void gemm_s_mfma(int bh0)
{
    __shared__ f16 Ah[128][40], Al[128][40], Bh[128][40], Bl[128][40];
    int lbh = blockIdx.z;
    int bh = bh0 + lbh;
    int b = bh >> 3, h = bh & 7;
    size_t base = (size_t)(b * H_ + h) * T_ * D_;
    const f16* QH = ap<f16>(Q_OFF);
    const f16* KH = ap<f16>(K_OFF);
    float* S = ap<float>(S_OFF);
    int m0 = blockIdx.x * 128, n0 = blockIdx.y * 128;
    int tid = threadIdx.x;
    int srow = tid >> 1, sseg = tid & 1;
    int am = m0 + srow, bnr = n0 + srow;
    int w = tid >> 6, l = tid & 63;
    int wm = (w >> 1) * 64, wn = (w & 1) * 64;
    int lr = l & 15, lk = (l >> 4) * 8;

    const f32x4 zf = {0.f, 0.f, 0.f, 0.f};
    f32x4 acc1[4][4], acc2[4][4];
#pragma unroll
    for (int i = 0; i < 4; i++)
#pragma unroll
        for (int j = 0; j < 4; j++) { acc1[i][j] = zf; acc2[i][j] = zf; }
    const int4 zz = make_int4(0, 0, 0, 0);

    for (int k0 = 0; k0 < 64; k0 += 32) {           // K=48, zero-padded to 64
        bool kv = (k0 + sseg * 16) < D_;            // 16-half chunks never straddle 48
        bool avv = kv && (am < T_);
        bool bvv = kv && (bnr < T_);
        size_t ao = base + (size_t)am * D_ + k0 + sseg * 16;
        size_t bo = base + (size_t)bnr * D_ + k0 + sseg * 16;
        int4 A0 = avv ? *(const int4*)(QH + ao)            : zz;
        int4 A1 = avv ? *(const int4*)(QH + ao + 8)        : zz;
        int4 A2 = avv ? *(const int4*)(QH + NRES + ao)     : zz;
        int4 A3 = avv ? *(const int4*)(QH + NRES + ao + 8) : zz;
        int4 B0 = bvv ? *(const int4*)(KH + bo)            : zz;
        int4 B1 = bvv ? *(const int4*)(KH + bo + 8)        : zz;
        int4 B2 = bvv ? *(const int4*)(KH + NRES + bo)     : zz;
        int4 B3 = bvv ? *(const int4*)(KH + NRES + bo + 8) : zz;
        *(int4*)&Ah[srow][sseg * 16]     = A0;
        *(int4*)&Ah[srow][sseg * 16 + 8] = A1;
        *(int4*)&Al[srow][sseg * 16]     = A2;
        *(int4*)&Al[srow][sseg * 16 + 8] = A3;
        *(int4*)&Bh[srow][sseg * 16]     = B0;
        *(int4*)&Bh[srow][sseg * 16 + 8] = B1;
        *(int4*)&Bl[srow][sseg * 16]     = B2;
        *(int4*)&Bl[srow][sseg * 16 + 8] = B3;
        __syncthreads();
        f16x8 fah[4], fal[4], fbh[4], fbl[4];
#pragma unroll
        for (int i = 0; i < 4; i++) {
            fah[i] = *(const f16x8*)&Ah[wm + i * 16 + lr][lk];
            fal[i] = *(const f16x8*)&Al[wm + i * 16 + lr][lk];
            fbh[i] = *(const f16x8*)&Bh[wn + i * 16 + lr][lk];
            fbl[i] = *(const f16x8*)&Bl[wn + i * 16 + lr][lk];
        }
#pragma unroll
        for (int i = 0; i < 4; i++)
#pragma unroll
            for (int j = 0; j < 4; j++) {
                acc1[i][j] = MFMA16(fah[i], fbh[j], acc1[i][j]);
                acc2[i][j] = MFMA16(fah[i], fbl[j], acc2[i][j]);
                acc2[i][j] = MFMA16(fal[i], fbh[j], acc2[i][j]);
            }
        __syncthreads();
    }

    const float scale = 0.14433756729740643f;
#pragma unroll
    for (int i = 0; i < 4; i++)
#pragma unroll
        for (int j = 0; j < 4; j++)
#pragma unroll
            for (int r = 0; r < 4; r++) {
                int m = m0 + wm + i * 16 + ((l >> 4) << 2) + r;
                int n = n0 + wn + j * 16 + lr;
                if (m < T_ && n < T_) {
                    float v = acc1[i][j][r] + acc2[i][j][r] * 0.000244140625f;
                    S[((size_t)lbh * T_ + m) * SP_ + n] = v * scale;
                }
            }
}

// ---------------- attention step 2: row softmax -> P hi/lo planes (pad to 800)
__global__ __launch_bounds__(256) void softmax_kernel()
{
    float* S = ap<float>(S_OFF);
    f16* PHp = ap<f16>(PH_OFF);
    f16* PLp = ap<f16>(PL_OFF);
    int wave = threadIdx.x >> 6, lane = threadIdx.x & 63;
    size_t row = (size_t)blockIdx.x * 4 + wave;
    float* p = S + row * SP_;
    float v[13];
    float m = -1e30f;
#pragma unroll
    for (int j = 0; j < 13; j++) {
        int idx = lane + 64 * j;
        v[j] = (idx < T_) ? p[idx] : -1e30f;
        m = fmaxf(m, v[j]);
    }
    for (int o = 32; o; o >>= 1) m = fmaxf(m, __shfl_down(m, o));
    m = __shfl(m, 0);
    float s = 0.f;
#pragma unroll
    for (int j = 0; j < 13; j++) { v[j] = expf(v[j] - m); s += v[j]; }
    for (int o = 32; o; o >>= 1) s += __shfl_down(s, o);
    s = __shfl(s, 0);
    float inv = 1.f / s;
#pragma unroll
    for (int j = 0; j < 13; j++) {
        int idx = lane + 64 * j;
        if (idx < PVT_) {
            float val = (idx < T_) ? v[j] * inv : 0.f;
            f16 h, lo; splitf(val, h, lo);
            PHp[row * PVT_ + idx] = h;
            PLp[row * PVT_ + idx] = lo;
        }
    }
}

// ---------------- attention step 3: O = P V (split MFMA, 128x48 tile, K=785)
__global__ __launch_bounds__(256, 2) void gemm_pv_mfma(int bh0)
{
    __shared__ f16 Ah[128][40], Al[128][40];
    __shared__ f16 Bh[48][40], Bl[48][40];
    int lbh = blockIdx.y;
    int bh = bh0 + lbh;
    int b = bh >> 3, h = bh & 7;
    const f16* PHp = ap<f16>(PH_OFF);
    const f16* PLp = ap<f16>(PL_OFF);
    const f16* VH = ap<f16>(V_OFF);
    size_t pbase = (size_t)lbh * T_ * PVT_;
    size_t vbase = (size_t)(b * H_ + h) * T_ * D_;
    int m0 = blockIdx.x * 128;
    int tid = threadIdx.x;
    int srow = tid >> 1, sseg = tid & 1;
    int am = m0 + srow;
    bool av = am < T_;
    int vtr = tid / 6, vds = tid - vtr * 6;     // B stage: 32 t-rows x 6 d-chunks
    bool bstage = tid < 192;
    int w = tid >> 6, l = tid & 63;
    int wr = w * 32;
    int lr = l & 15, lk = (l >> 4) * 8;

    const f32x4 zf = {0.f, 0.f, 0.f, 0.f};
    f32x4 acc1[2][3], acc2[2][3];
#pragma unroll
    for (int i = 0; i < 2; i++)
#pragma unroll
        for (int j = 0; j < 3; j++) { acc1[i][j] = zf; acc2[i][j] = zf; }
    const int4 zz = make_int4(0, 0, 0, 0);

    for (int k0 = 0; k0 < PVT_; k0 += 32) {
        // A: P planes (rows padded with zeros to 800 by softmax)
        size_t ao = pbase + (size_t)am * PVT_ + k0 + sseg * 16;
        int4 a0 = av ? *(const int4*)(PHp + ao)     : zz;
        int4 a1 = av ? *(const int4*)(PHp + ao + 8) : zz;
        int4 a2 = av ? *(const int4*)(PLp + ao)     : zz;
        int4 a3 = av ? *(const int4*)(PLp + ao + 8) : zz;
        *(int4*)&Ah[srow][sseg * 16]     = a0;
        *(int4*)&Ah[srow][sseg * 16 + 8] = a1;
        *(int4*)&Al[srow][sseg * 16]     = a2;
        *(int4*)&Al[srow][sseg * 16 + 8] = a3;
        // B: V[t][d] -> LDS transpose [d][t_local]
        if (bstage) {
            int kt = k0 + vtr;
            bool bv = kt < T_;
            size_t vo = vbase + (size_t)kt * D_ + vds * 8;
            f16x8 vh = {0, 0, 0, 0, 0, 0, 0, 0};
            f16x8 vl = {0, 0, 0, 0, 0, 0, 0, 0};
            if (bv) {
                vh = *(const f16x8*)(VH + vo);
                vl = *(const f16x8*)(VH + NRES + vo);
            }
#pragma unroll
            for (int jj = 0; jj < 8; jj++) {
                Bh[vds * 8 + jj][vtr] = vh[jj];
                Bl[vds * 8 + jj][vtr] = vl[jj];
            }
        }
        __syncthreads();
        f16x8 pa[2], pl2[2], vb[3], vbl[3];
#pragma unroll
        for (int i = 0; i < 2; i++) {
            pa[i]  = *(const f16x8*)&Ah[wr + i * 16 + lr][lk];
            pl2[i] = *(const f16x8*)&Al[wr + i * 16 + lr][lk];
        }
#pragma unroll
        for (int j = 0; j < 3; j++) {
            vb[j]  = *(const f16x8*)&Bh[j * 16 + lr][lk];
            vbl[j] = *(const f16x8*)&Bl[j * 16 + lr][lk];
        }
#pragma unroll
        for (int i = 0; i < 2; i++)
#pragma unroll
            for (int j = 0; j < 3; j++) {
                acc1[i][j] = MFMA16(pa[i], vb[j], acc1[i][j]);
                acc2[i][j] = MFMA16(pa[i], vbl[j], acc2[i][j]);
                acc2[i][j] = MFMA16(pl2[i], vb[j], acc2[i][j]);
            }
        __syncthreads();
    }

    f16* AH = ap<f16>(ATT_OFF);
#pragma unroll
    for (int i = 0; i < 2; i++)
#pragma unroll
        for (int j = 0; j < 3; j++)
#pragma unroll
            for (int r = 0; r < 4; r++) {
                int m = m0 + wr + i * 16 + ((l >> 4) << 2) + r;
                if (m >= T_) continue;
                int d = j * 16 + lr;
                float v = acc1[i][j][r] + acc2[i][j][r] * 0.000244140625f;
                size_t idx = (size_t)(b * T_ + m) * C_ + h * D_ + d;
                f16 hv, lv; splitf(v, hv, lv);
                AH[idx] = hv;
                AH[NRES + idx] = lv;
            }
}

// ---------------- ci stage A/B (double)
__global__ __launch_bounds__(384) void cia_kernel()
{
    int b = blockIdx.x, s = blockIdx.y, c = threadIdx.x;
    const float* xm = ap<float>(XM_OFF);
    const int SL = (T_ + 7) / 8;
    int t0 = s * SL, t1 = min(t0 + SL, T_);
    double sm = 0.0;
    for (int t = t0; t < t1; t++) sm += (double)xm[((size_t)b * T_ + t) * C_ + c];
    ap<double>(CIP_OFF)[((size_t)b * 8 + s) * C_ + c] = sm;
}

__global__ __launch_bounds__(384) void cib_kernel()
{
    int b = blockIdx.x, c = threadIdx.x;
    const double* pp = ap<double>(CIP_OFF);
    double sm = 0.0;
#pragma unroll
    for (int s = 0; s < 8; s++) sm += pp[((size_t)b * 8 + s) * C_ + c];
    sm /= (double)T_;
    ap<double>(CID_OFF)[b * C_ + c] = 1.0 / (1.0 + exp(-sm));
}

// ---------------- ca (double)
__global__ __launch_bounds__(64) void ca_kernel()
{
    const float* xres1 = ap<float>(RES_OFF);
    const double* ci   = ap<double>(CID_OFF);
    int idx = blockIdx.x;
    int b = idx / HW_, n = idx - b * HW_;
    int lane = threadIdx.x;
    double s = 0.0;
    for (int c = lane; c < C_; c += 64)
        s += (double)xres1[((size_t)b * T_ + 1 + n) * C_ + c] * ci[b * C_ + c];
    for (int o = 32; o; o >>= 1) s += __shfl_down(s, o);
    if (lane == 0) ap<double>(CAD_OFF)[idx] = s;
}

// ---------------- stable rank
__global__ __launch_bounds__(256) void rank_kernel()
{
    const double* ca = ap<double>(CAD_OFF);
    int* perm = ap<int>(PERM_OFF);
    int b = blockIdx.x, tid = threadIdx.x;
    __shared__ double cs[HW_];
    for (int i = tid; i < HW_; i += 256) cs[i] = ca[b * HW_ + i];
    __syncthreads();
    for (int i = tid; i < HW_; i += 256) {
        double vi = cs[i];
        int r = 0;
        for (int j = 0; j < HW_; j++) {
            double vj = cs[j];
            r += (vj < vi) || (vj == vi && j < i);
        }
        if (r >= HW_ - TP_ + 1) perm[b * (TP_ - 1) + (r - (HW_ - TP_ + 1))] = i;
    }
}

// ---------------- LN2 A/B/apply
__global__ __launch_bounds__(256) void ln2a_kernel()
{
    const float* xres1 = ap<float>(RES_OFF);
    const int* perm = ap<int>(PERM_OFF);
    const int TC = TP_ * C_;
    const int SL = (TC + 7) / 8;
    int b = blockIdx.x, s = blockIdx.y, tid = threadIdx.x;
    int e0 = s * SL, e1 = min(e0 + SL, TC);
    __shared__ double r1[256], r2[256];
    double sm = 0.0, s2 = 0.0;
    for (int e = e0 + tid; e < e1; e += 256) {
        int t = e / C_, c = e - t * C_;
        int st = (t == 0) ? 0 : 1 + perm[b * (TP_ - 1) + t - 1];
        double v = (double)xres1[((size_t)b * T_ + st) * C_ + c];
        sm += v; s2 += v * v;
    }
    r1[tid] = sm; r2[tid] = s2; __syncthreads();
    for (int o = 128; o; o >>= 1) {
        if (tid < o) { r1[tid] += r1[tid + o]; r2[tid] += r2[tid + o]; }
        __syncthreads();
    }
    if (tid == 0) {
        double2* ps = ap<double2>(L2PS_OFF);
        ps[b * 8 + s] = make_double2(r1[0], r2[0]);
    }
}

__global__ __launch_bounds__(64) void ln2b_kernel()
{
    int b = blockIdx.x, lane = threadIdx.x;
    const double2* ps = ap<double2>(L2PS_OFF);
    double sm = 0.0, s2 = 0.0;
    if (lane < 8) { sm = ps[b * 8 + lane].x; s2 = ps[b * 8 + lane].y; }
    for (int o = 4; o; o >>= 1) { sm += __shfl_down(sm, o); s2 += __shfl_down(s2, o); }
    if (lane == 0) {
        const int TC = TP_ * C_;
        double m = sm / TC;
        double var = s2 / TC - m * m;
        ap<float>(L2MU_OFF)[b] = (float)m;
        ap<float>(L2RS_OFF)[b] = (float)(1.0 / sqrt(var + 1e-5));
    }
}

__global__ __launch_bounds__(256) void ln2_apply_kernel()
{
    size_t i = (size_t)blockIdx.x * 256 + threadIdx.x;
    if (i >= NX2) return;
    const int TC = TP_ * C_;
    int b = (int)(i / TC);
    int e = (int)(i - (size_t)b * TC);
    int t = e / C_, c = e - t * C_;
    const int* perm = ap<int>(PERM_OFF);
    int st = (t == 0) ? 0 : 1 + perm[b * (TP_ - 1) + t - 1];
    float v = ap<float>(RES_OFF)[((size_t)b * T_ + st) * C_ + c];
    float r = (v - ap<float>(L2MU_OFF)[b]) * ap<float>(L2RS_OFF)[b]
              * ap<float>(LN2W_OFF)[e] + ap<float>(LN2B_OFF)[e];
    ap<float>(X2N_OFF)[i] = r;
    f16 h, l; splitf(r, h, l);
    ap<f16>(X2NH_OFF)[i] = h;
    ap<f16>(X2NL_OFF)[i] = l;
}

// ---------------- FFN2 reduce: 2 split-K partials + x2n resid -> split store
__global__ __launch_bounds__(256) void ffn2_reduce_kernel(float* __restrict__ out)
{
    const size_t tot = NX2;
    size_t i = (size_t)blockIdx.x * 256 + threadIdx.x;
    if (i >= tot) return;
    const float* part = ap<float>(PART_OFF);
    float v = part[i] + part[tot + i] + ap<float>(X2N_OFF)[i];
    int gm = (int)(i / C_);
    int gn = (int)(i - (size_t)gm * C_);
    int b = gm / TP_, t = gm - b * TP_;
    size_t off = (t == 0)
        ? ((size_t)B_ * (TP_ - 1) * C_ + (size_t)b * C_ + gn)
        : ((size_t)(b * (TP_ - 1) + (t - 1)) * C_ + gn);
    out[off] = v;
}

extern "C" void kernel_launch(void* const* d_in, const int* in_sizes, int n_in,
                              void* d_out, int out_size, void* d_ws, size_t ws_size,
                              hipStream_t stream)
{
    float* out = (float*)d_out;
    (void)d_ws; (void)ws_size; (void)in_sizes; (void)n_in; (void)out_size;

    const int M1 = B_ * T_;            // 25120
    const int M2 = B_ * TP_;           // 6304
    const int GM1 = (M1 + 127) / 128;  // 197
    const int GM2 = (M2 + 127) / 128;  // 50
    const int GT  = (T_ + 127) / 128;  // 7

    // 0. dtype detect + merged conversion + weight split
    detect_kernel<<<1, 64, 0, stream>>>((const unsigned*)d_in[2]);
    SrcPtrs sp;
    for (int i = 0; i < 12; i++) sp.p[i] = d_in[i];
    cvt_all_kernel<<<(int)((NTOT_CVT + 255) / 256), 256, 0, stream>>>(sp);
    cvt_wsplit_kernel<<<(int)((4 * NWP + 2 * NW1 + 255) / 256), 256, 0, stream>>>();

    // 1. LN1 (emits X1 hi/lo planes)
    stats1a_kernel<<<dim3(B_, 16), 256, 0, stream>>>();
    stats1b_kernel<<<B_, 64, 0, stream>>>();
    ln1_apply_kernel<<<(int)((NRES + 255) / 256), 256, 0, stream>>>();

    // 2. merged QKV projection (split MFMA, routed to per-head hi/lo planes)
    gemm_mfma<5><<<dim3(GM1, (3 * C_) / 128), 256, 0, stream>>>(
        X1_OFF, X1_OFF + NRES * 2, WPH_OFF, WPL_OFF, 0, M1, 3 * C_, C_);

    // 3. attention (split MFMA S and PV, softmax emits P planes)
    for (int bh0 = 0; bh0 < B_ * H_; bh0 += CH_) {
        gemm_s_mfma<<<dim3(GT, GT, CH_), 256, 0, stream>>>(bh0);
        softmax_kernel<<<CH_ * T_ / 4, 256, 0, stream>>>();
        gemm_pv_mfma<<<dim3(GT, CH_), 256, 0, stream>>>(bh0);
    }
    // Wo projection fused with residual (split MFMA)
    gemm_mfma<4><<<dim3(GM1, C_ / 128), 256, 0, stream>>>(
        ATT_OFF, ATT_OFF + NRES * 2, WPH_OFF + 3 * NWP * 2, WPL_OFF + 3 * NWP * 2,
        XM_OFF, M1, C_, C_);

    // 4. ci, ca, rank, LN2 (fp32/fp64 ordering path unchanged)
    cia_kernel<<<dim3(B_, 8), 384, 0, stream>>>();
    cib_kernel<<<B_, 384, 0, stream>>>();
    ca_kernel<<<B_ * HW_, 64, 0, stream>>>();
    rank_kernel<<<B_, 256, 0, stream>>>();
    ln2a_kernel<<<dim3(B_, 8), 256, 0, stream>>>();
    ln2b_kernel<<<B_, 64, 0, stream>>>();
    ln2_apply_kernel<<<(int)((NX2 + 255) / 256), 256, 0, stream>>>();

    // 5. FFN: gelu GEMM -> H planes, split-K=2 GEMM + reduce
    gemm_mfma<2><<<dim3(GM2, FF_ / 128), 256, 0, stream>>>(
        X2NH_OFF, X2NL_OFF, WFH_OFF, WFL_OFF, H_OFF, M2, FF_, C_);
    gemm_mfma<6><<<dim3(GM2, C_ / 128, 2), 256, 0, stream>>>(
        H_OFF, H_OFF + NH * 2, WFH_OFF + NW1 * 2, WFL_OFF + NW1 * 2, 0, M2, C_, FF_);
    ffn2_reduce_kernel<<<(int)((NX2 + 255) / 256), 256, 0, stream>>>(out);
}